// Round 1
// baseline (309.773 us; speedup 1.0000x reference)
//
#include <hip/hip_runtime.h>
#include <hip/hip_bf16.h>
#include <math.h>

typedef short short8 __attribute__((ext_vector_type(8)));
typedef short short4v __attribute__((ext_vector_type(4)));
typedef float f32x4 __attribute__((ext_vector_type(4)));

__device__ __forceinline__ short f2bf(float f) {
  union { float f; unsigned u; } v; v.f = f;
  unsigned r = v.u + 0x7FFFu + ((v.u >> 16) & 1u);
  return (short)(r >> 16);
}
__device__ __forceinline__ float bf2f(short s) {
  union { unsigned u; float f; } v; v.u = ((unsigned)(unsigned short)s) << 16;
  return v.f;
}

// -------- generic f32 -> bf16 cast, 4 elems/thread (sizes are all /4) -----
__global__ __launch_bounds__(256) void cast_kernel(const float* __restrict__ in,
                                                   short* __restrict__ out, int n4) {
  int i = blockIdx.x * blockDim.x + threadIdx.x;
  if (i < n4) {
    float4 v = ((const float4*)in)[i];
    short4v o;
    o.x = f2bf(v.x); o.y = f2bf(v.y); o.z = f2bf(v.z); o.w = f2bf(v.w);
    ((short4v*)out)[i] = o;
  }
}

// -------- DCT matrix: D[k][n] = 2*cos(pi/(2N) * k * (2n+1)), N=1024 -------
__global__ __launch_bounds__(256) void build_D(short* __restrict__ D) {
  int t = blockIdx.x * 256 + threadIdx.x;   // 1024*1024 total
  int k = t >> 10, n = t & 1023;
  const float s = 1.5339807878856412e-03f;  // pi/2048 (fp32, mirrors ref order)
  float arg = (s * (float)k) * (float)(2 * n + 1);
  D[t] = f2bf(2.0f * cosf(arg));
}

// -------- LayerNorm over k for freqT[b][k][c] (in place, bf16) ------------
__global__ __launch_bounds__(256) void ln_kernel(short* __restrict__ freqT,
                                                 const float* __restrict__ lnw,
                                                 const float* __restrict__ lnb) {
  int b  = blockIdx.x >> 2;
  int c0 = (blockIdx.x & 3) * 128;
  int cl = threadIdx.x & 127;
  int kg = threadIdx.x >> 7;           // 0..1
  short* base = freqT + ((size_t)b << 19) + c0 + cl;
  float s = 0.f, ss = 0.f;
  for (int k = kg * 512; k < kg * 512 + 512; ++k) {
    float v = bf2f(base[(size_t)k * 512]);
    s += v; ss += v * v;
  }
  __shared__ float redS[2][128], redQ[2][128];
  redS[kg][cl] = s; redQ[kg][cl] = ss;
  __syncthreads();
  float S = redS[0][cl] + redS[1][cl];
  float Q = redQ[0][cl] + redQ[1][cl];
  float mu  = S * (1.f / 1024.f);
  float var = Q * (1.f / 1024.f) - mu * mu;   // biased, like nn.LayerNorm
  float rstd = rsqrtf(var + 1e-6f);
  for (int k = kg * 512; k < kg * 512 + 512; ++k) {
    float v = bf2f(base[(size_t)k * 512]);
    float h = (v - mu) * rstd * lnw[k] + lnb[k];
    base[(size_t)k * 512] = f2bf(h);
  }
}

// -------- BT-form bf16 GEMM: C[m,n] = sum_k A[m,k]*B[n,k] -----------------
// 128x128 tile, BK=32, 4 waves (2x2), 16x16x32 MFMA, global_load_lds staging.
// EPI 0: C -> freqT[b][r][c] bf16 (b=col>>9, c=col&511), r = row (k index)
// EPI 1: relu -> z1t[bz][r][col] bf16
// EPI 2: out[bz][r][col] = X[same] * sigmoid(C), fp32
template<int EPI>
__global__ __launch_bounds__(256) void gemm_bt(
    const short* __restrict__ A, const short* __restrict__ B,
    void* __restrict__ Cout, const float* __restrict__ X,
    int M, int N, int K, long strideA, long strideB)
{
  __shared__ short As[128 * 32];
  __shared__ short Bs[128 * 32];
  const int tid  = threadIdx.x;
  const int lane = tid & 63;
  const int wave = tid >> 6;
  const int wr = wave >> 1, wc = wave & 1;
  const int bz = blockIdx.z;
  const long row0 = (long)blockIdx.x * 128;
  const long col0 = (long)blockIdx.y * 128;
  const short* Ab = A + (size_t)bz * strideA + (size_t)row0 * K;
  const short* Bb = B + (size_t)bz * strideB + (size_t)col0 * K;

  f32x4 acc[4][4];
#pragma unroll
  for (int i = 0; i < 4; ++i)
#pragma unroll
    for (int j = 0; j < 4; ++j) acc[i][j] = (f32x4){0.f, 0.f, 0.f, 0.f};

  const int lr = lane & 15;
  const int lk = (lane >> 4) * 8;

  for (int k0 = 0; k0 < K; k0 += 32) {
#pragma unroll
    for (int i = 0; i < 2; ++i) {
      int ci = i * 256 + tid;              // chunk id 0..511 (16B chunks)
      int rr = ci >> 2;                    // tile row
      int kc = (ci & 3) * 8;               // k offset within BK
      __builtin_amdgcn_global_load_lds(
          (const __attribute__((address_space(1))) void*)(Ab + (size_t)rr * K + k0 + kc),
          (__attribute__((address_space(3))) void*)(As + ci * 8), 16, 0, 0);
      __builtin_amdgcn_global_load_lds(
          (const __attribute__((address_space(1))) void*)(Bb + (size_t)rr * K + k0 + kc),
          (__attribute__((address_space(3))) void*)(Bs + ci * 8), 16, 0, 0);
    }
    __syncthreads();

    short8 af[4], bfv[4];
#pragma unroll
    for (int mi = 0; mi < 4; ++mi)
      af[mi] = *(const short8*)&As[(wr * 64 + mi * 16 + lr) * 32 + lk];
#pragma unroll
    for (int ni = 0; ni < 4; ++ni)
      bfv[ni] = *(const short8*)&Bs[(wc * 64 + ni * 16 + lr) * 32 + lk];
#pragma unroll
    for (int mi = 0; mi < 4; ++mi)
#pragma unroll
      for (int ni = 0; ni < 4; ++ni)
        acc[mi][ni] = __builtin_amdgcn_mfma_f32_16x16x32_bf16(af[mi], bfv[ni], acc[mi][ni], 0, 0, 0);
    __syncthreads();
  }

  const int rbase = (int)row0 + wr * 64 + ((lane >> 4) << 2);
  const int cbase = (int)col0 + wc * 64 + lr;
#pragma unroll
  for (int mi = 0; mi < 4; ++mi) {
#pragma unroll
    for (int ni = 0; ni < 4; ++ni) {
#pragma unroll
      for (int j = 0; j < 4; ++j) {
        int r  = rbase + mi * 16 + j;
        int cc = cbase + ni * 16;
        float v = acc[mi][ni][j];
        if (EPI == 0) {
          size_t idx = ((size_t)(cc >> 9) << 19) + (size_t)r * 512 + (size_t)(cc & 511);
          ((short*)Cout)[idx] = f2bf(v);
        } else if (EPI == 1) {
          size_t idx = (size_t)bz * 1048576 + (size_t)r * 1024 + (size_t)cc;
          ((short*)Cout)[idx] = f2bf(v > 0.f ? v : 0.f);
        } else {
          size_t idx = (size_t)bz * 524288 + (size_t)r * 1024 + (size_t)cc;
          float g = 1.f / (1.f + __expf(-v));
          ((float*)Cout)[idx] = X[idx] * g;
        }
      }
    }
  }
}

extern "C" void kernel_launch(void* const* d_in, const int* in_sizes, int n_in,
                              void* d_out, int out_size, void* d_ws, size_t ws_size,
                              hipStream_t stream) {
  const float* x    = (const float*)d_in[0];   // [32,512,1024]
  const float* w1   = (const float*)d_in[1];   // [1024,512]
  const float* w2   = (const float*)d_in[2];   // [512,1024]
  const float* ln_w = (const float*)d_in[3];   // [1024]
  const float* ln_b = (const float*)d_in[4];   // [1024]
  float* out = (float*)d_out;

  char* ws = (char*)d_ws;
  short* x_bf  = (short*)(ws);                  // 33,554,432 B
  short* D_bf  = (short*)(ws + 33554432);       //  2,097,152 B
  short* w1_bf = (short*)(ws + 35651584);       //  1,048,576 B
  short* w2_bf = (short*)(ws + 36700160);       //  1,048,576 B
  short* freqT = (short*)(ws + 37748736);       // 33,554,432 B  [b][k][c]
  short* z1t   = (short*)(ws + 71303168);       // 67,108,864 B  [b][p][o]
  // total 138,412,032 B

  cast_kernel<<<dim3(16384), dim3(256), 0, stream>>>(x,  x_bf,  16777216 / 4);
  cast_kernel<<<dim3(512),   dim3(256), 0, stream>>>(w1, w1_bf, 524288 / 4);
  cast_kernel<<<dim3(512),   dim3(256), 0, stream>>>(w2, w2_bf, 524288 / 4);
  build_D<<<dim3(4096), dim3(256), 0, stream>>>(D_bf);

  // GEMM1: C[k,(b,c)] = sum_n D[k,n] * x[(b,c),n]  -> freqT[b][k][c]
  gemm_bt<0><<<dim3(8, 128, 1), dim3(256), 0, stream>>>(
      D_bf, x_bf, (void*)freqT, nullptr, 1024, 16384, 1024, 0, 0);

  // LayerNorm over k, in place -> Ht[b][p][c]
  ln_kernel<<<dim3(128), dim3(256), 0, stream>>>(freqT, ln_w, ln_b);

  // GEMM2: C[p,o] = sum_c Ht[b][p,c] * w1[o,c], relu -> z1t[b][p][o]
  gemm_bt<1><<<dim3(8, 8, 32), dim3(256), 0, stream>>>(
      freqT, w1_bf, (void*)z1t, nullptr, 1024, 1024, 512, 524288, 0);

  // GEMM3: C[o2,p] = sum_j w2[o2,j] * z1t[b][p,j]; out = x * sigmoid(C)
  gemm_bt<2><<<dim3(4, 8, 32), dim3(256), 0, stream>>>(
      w2_bf, z1t, (void*)out, x, 512, 1024, 1024, 0, 1048576);
}

// Round 2
// 231.257 us; speedup vs baseline: 1.3395x; 1.3395x over previous
//
#include <hip/hip_runtime.h>
#include <hip/hip_bf16.h>
#include <math.h>

typedef short short8 __attribute__((ext_vector_type(8)));
typedef short short4v __attribute__((ext_vector_type(4)));
typedef float f32x4 __attribute__((ext_vector_type(4)));

__device__ __forceinline__ short f2bf(float f) {
  union { float f; unsigned u; } v; v.f = f;
  unsigned r = v.u + 0x7FFFu + ((v.u >> 16) & 1u);
  return (short)(r >> 16);
}
__device__ __forceinline__ float bf2f(short s) {
  union { unsigned u; float f; } v; v.u = ((unsigned)(unsigned short)s) << 16;
  return v.f;
}

// -------- generic f32 -> bf16 cast, 4 elems/thread (sizes are all /4) -----
__global__ __launch_bounds__(256) void cast_kernel(const float* __restrict__ in,
                                                   short* __restrict__ out, int n4) {
  int i = blockIdx.x * blockDim.x + threadIdx.x;
  if (i < n4) {
    float4 v = ((const float4*)in)[i];
    short4v o;
    o.x = f2bf(v.x); o.y = f2bf(v.y); o.z = f2bf(v.z); o.w = f2bf(v.w);
    ((short4v*)out)[i] = o;
  }
}

// -------- DCT matrix: D[k][n] = 2*cos(pi/(2N) * k * (2n+1)), N=1024 -------
__global__ __launch_bounds__(256) void build_D(short* __restrict__ D) {
  int t = blockIdx.x * 256 + threadIdx.x;   // 1024*1024 total
  int k = t >> 10, n = t & 1023;
  const float s = 1.5339807878856412e-03f;  // pi/2048
  float arg = (s * (float)k) * (float)(2 * n + 1);
  D[t] = f2bf(2.0f * cosf(arg));
}

// -------- fold 8 row-block partials -> per-(b,c) mu, rstd -----------------
__global__ __launch_bounds__(256) void ln_stats(const float2* __restrict__ partial,
                                                float2* __restrict__ musd) {
  int n = blockIdx.x * 256 + threadIdx.x;   // 16384
  float S = 0.f, Q = 0.f;
#pragma unroll
  for (int r = 0; r < 8; ++r) {
    float2 p = partial[(size_t)r * 16384 + n];
    S += p.x; Q += p.y;
  }
  float mu  = S * (1.f / 1024.f);
  float var = Q * (1.f / 1024.f) - mu * mu;   // biased, like nn.LayerNorm
  float2 o; o.x = mu; o.y = rsqrtf(var + 1e-6f);
  musd[n] = o;
}

// -------- streaming LN apply: freqT[b][k][c] in place, short8/thread ------
__global__ __launch_bounds__(256) void ln_apply(short* __restrict__ freqT,
                                                const float2* __restrict__ musd,
                                                const float* __restrict__ lnw,
                                                const float* __restrict__ lnb) {
  int t = blockIdx.x * 256 + threadIdx.x;   // 2,097,152 threads
  int c8 = t & 63;            // c chunk (8 elems)
  int k  = (t >> 6) & 1023;
  int b  = t >> 16;
  size_t idx = ((size_t)b << 19) + (size_t)k * 512 + (size_t)c8 * 8;
  short8 v = *(const short8*)&freqT[idx];
  float w  = lnw[k];
  float bb = lnb[k];
  const float2* ms = &musd[b * 512 + c8 * 8];
  short8 o;
#pragma unroll
  for (int j = 0; j < 8; ++j) {
    float f = bf2f(v[j]);
    float2 m = ms[j];
    o[j] = f2bf((f - m.x) * m.y * w + bb);
  }
  *(short8*)&freqT[idx] = o;
}

// -------- BT-form bf16 GEMM: C[m,n] = sum_k A[m,k]*B[n,k] -----------------
// 128x128 tile, BK=32, 4 waves (2x2), 16x16x32 MFMA, global_load_lds staging.
// EPI 0: C -> freqT[b][r][c] bf16 (b=col>>9, c=col&511); also reduce per-col
//        sum/sumsq over the block's 128 rows -> P[blockIdx.x*16384 + col]
// EPI 1: relu -> z1t[bz][r][col] bf16
// EPI 2: out[bz][r][col] = X[same] * sigmoid(C), fp32
template<int EPI>
__global__ __launch_bounds__(256) void gemm_bt(
    const short* __restrict__ A, const short* __restrict__ B,
    void* __restrict__ Cout, const float* __restrict__ X,
    float2* __restrict__ P,
    int M, int N, int K, long strideA, long strideB)
{
  __shared__ short As[128 * 32];
  __shared__ short Bs[128 * 32];
  const int tid  = threadIdx.x;
  const int lane = tid & 63;
  const int wave = tid >> 6;
  const int wr = wave >> 1, wc = wave & 1;
  const int bz = blockIdx.z;
  const long row0 = (long)blockIdx.x * 128;
  const long col0 = (long)blockIdx.y * 128;
  const short* Ab = A + (size_t)bz * strideA + (size_t)row0 * K;
  const short* Bb = B + (size_t)bz * strideB + (size_t)col0 * K;

  f32x4 acc[4][4];
#pragma unroll
  for (int i = 0; i < 4; ++i)
#pragma unroll
    for (int j = 0; j < 4; ++j) acc[i][j] = (f32x4){0.f, 0.f, 0.f, 0.f};

  const int lr = lane & 15;
  const int lk = (lane >> 4) * 8;

  for (int k0 = 0; k0 < K; k0 += 32) {
#pragma unroll
    for (int i = 0; i < 2; ++i) {
      int ci = i * 256 + tid;              // chunk id 0..511 (16B chunks)
      int rr = ci >> 2;                    // tile row
      int kc = (ci & 3) * 8;               // k offset within BK
      __builtin_amdgcn_global_load_lds(
          (const __attribute__((address_space(1))) void*)(Ab + (size_t)rr * K + k0 + kc),
          (__attribute__((address_space(3))) void*)(As + ci * 8), 16, 0, 0);
      __builtin_amdgcn_global_load_lds(
          (const __attribute__((address_space(1))) void*)(Bb + (size_t)rr * K + k0 + kc),
          (__attribute__((address_space(3))) void*)(Bs + ci * 8), 16, 0, 0);
    }
    __syncthreads();

    short8 af[4], bfv[4];
#pragma unroll
    for (int mi = 0; mi < 4; ++mi)
      af[mi] = *(const short8*)&As[(wr * 64 + mi * 16 + lr) * 32 + lk];
#pragma unroll
    for (int ni = 0; ni < 4; ++ni)
      bfv[ni] = *(const short8*)&Bs[(wc * 64 + ni * 16 + lr) * 32 + lk];
#pragma unroll
    for (int mi = 0; mi < 4; ++mi)
#pragma unroll
      for (int ni = 0; ni < 4; ++ni)
        acc[mi][ni] = __builtin_amdgcn_mfma_f32_16x16x32_bf16(af[mi], bfv[ni], acc[mi][ni], 0, 0, 0);
    __syncthreads();
  }

  const int rbase = (int)row0 + wr * 64 + ((lane >> 4) << 2);
  const int cbase = (int)col0 + wc * 64 + lr;

  float s[4], q[4];
#pragma unroll
  for (int ni = 0; ni < 4; ++ni) { s[ni] = 0.f; q[ni] = 0.f; }

#pragma unroll
  for (int mi = 0; mi < 4; ++mi) {
#pragma unroll
    for (int ni = 0; ni < 4; ++ni) {
#pragma unroll
      for (int j = 0; j < 4; ++j) {
        int r  = rbase + mi * 16 + j;
        int cc = cbase + ni * 16;
        float v = acc[mi][ni][j];
        if (EPI == 0) {
          s[ni] += v; q[ni] += v * v;
          size_t idx = ((size_t)(cc >> 9) << 19) + (size_t)r * 512 + (size_t)(cc & 511);
          ((short*)Cout)[idx] = f2bf(v);
        } else if (EPI == 1) {
          size_t idx = (size_t)bz * 1048576 + (size_t)r * 1024 + (size_t)cc;
          ((short*)Cout)[idx] = f2bf(v > 0.f ? v : 0.f);
        } else {
          size_t idx = (size_t)bz * 524288 + (size_t)r * 1024 + (size_t)cc;
          float g = 1.f / (1.f + __expf(-v));
          ((float*)Cout)[idx] = X[idx] * g;
        }
      }
    }
  }

  if (EPI == 0) {
    // Reduce per-column sum/sumsq over the block's 128 rows.
    // LDS reuse (safe: loop ends with __syncthreads after last MFMA reads).
    float* redS = (float*)As;   // [128 cols][8 contributors]
    float* redQ = (float*)Bs;
    const int contrib = wr * 4 + (lane >> 4);
#pragma unroll
    for (int ni = 0; ni < 4; ++ni) {
      int ccl = wc * 64 + ni * 16 + lr;    // 0..127 within block
      redS[ccl * 8 + contrib] = s[ni];
      redQ[ccl * 8 + contrib] = q[ni];
    }
    __syncthreads();
    if (tid < 128) {
      float S = 0.f, Q = 0.f;
#pragma unroll
      for (int i = 0; i < 8; ++i) { S += redS[tid * 8 + i]; Q += redQ[tid * 8 + i]; }
      float2 o; o.x = S; o.y = Q;
      P[(size_t)blockIdx.x * 16384 + col0 + tid] = o;
    }
  }
}

extern "C" void kernel_launch(void* const* d_in, const int* in_sizes, int n_in,
                              void* d_out, int out_size, void* d_ws, size_t ws_size,
                              hipStream_t stream) {
  const float* x    = (const float*)d_in[0];   // [32,512,1024]
  const float* w1   = (const float*)d_in[1];   // [1024,512]
  const float* w2   = (const float*)d_in[2];   // [512,1024]
  const float* ln_w = (const float*)d_in[3];   // [1024]
  const float* ln_b = (const float*)d_in[4];   // [1024]
  float* out = (float*)d_out;

  char* ws = (char*)d_ws;
  short* x_bf   = (short*)(ws);                  // 33,554,432 B
  short* D_bf   = (short*)(ws + 33554432);       //  2,097,152 B
  short* w1_bf  = (short*)(ws + 35651584);       //  1,048,576 B
  short* w2_bf  = (short*)(ws + 36700160);       //  1,048,576 B
  short* freqT  = (short*)(ws + 37748736);       // 33,554,432 B  [b][k][c]
  short* z1t    = (short*)(ws + 71303168);       // 67,108,864 B  [b][p][o]
  float2* part  = (float2*)(ws + 138412032);     //  1,048,576 B  [8][16384]
  float2* musd  = (float2*)(ws + 139460608);     //    131,072 B  [16384]
  // total ~139.6 MB

  cast_kernel<<<dim3(16384), dim3(256), 0, stream>>>(x,  x_bf,  16777216 / 4);
  cast_kernel<<<dim3(512),   dim3(256), 0, stream>>>(w1, w1_bf, 524288 / 4);
  cast_kernel<<<dim3(512),   dim3(256), 0, stream>>>(w2, w2_bf, 524288 / 4);
  build_D<<<dim3(4096), dim3(256), 0, stream>>>(D_bf);

  // GEMM1: C[k,(b,c)] = sum_n D[k,n] * x[(b,c),n] -> freqT[b][k][c] + LN partials
  gemm_bt<0><<<dim3(8, 128, 1), dim3(256), 0, stream>>>(
      D_bf, x_bf, (void*)freqT, nullptr, part, 1024, 16384, 1024, 0, 0);

  // LN stats: fold 8 row-block partials -> (mu, rstd) per (b,c)
  ln_stats<<<dim3(64), dim3(256), 0, stream>>>(part, musd);

  // LN apply: normalize freqT in place (streaming, vectorized)
  ln_apply<<<dim3(8192), dim3(256), 0, stream>>>(freqT, musd, ln_w, ln_b);

  // GEMM2: C[p,o] = sum_c Ht[b][p,c] * w1[o,c], relu -> z1t[b][p][o]
  gemm_bt<1><<<dim3(8, 8, 32), dim3(256), 0, stream>>>(
      freqT, w1_bf, (void*)z1t, nullptr, nullptr, 1024, 1024, 512, 524288, 0);

  // GEMM3: C[o2,p] = sum_j w2[o2,j] * z1t[b][p,j]; out = x * sigmoid(C)
  gemm_bt<2><<<dim3(4, 8, 32), dim3(256), 0, stream>>>(
      w2_bf, z1t, (void*)out, x, nullptr, 512, 1024, 1024, 0, 1048576);
}

// Round 3
// 216.355 us; speedup vs baseline: 1.4318x; 1.0689x over previous
//
#include <hip/hip_runtime.h>
#include <hip/hip_bf16.h>
#include <math.h>

typedef short short8 __attribute__((ext_vector_type(8)));
typedef short short4v __attribute__((ext_vector_type(4)));
typedef float f32x4 __attribute__((ext_vector_type(4)));

__device__ __forceinline__ short f2bf(float f) {
  union { float f; unsigned u; } v; v.f = f;
  unsigned r = v.u + 0x7FFFu + ((v.u >> 16) & 1u);
  return (short)(r >> 16);
}
__device__ __forceinline__ float bf2f(short s) {
  union { unsigned u; float f; } v; v.u = ((unsigned)(unsigned short)s) << 16;
  return v.f;
}

// -------- generic f32 -> bf16 cast, 4 elems/thread (sizes are all /4) -----
__global__ __launch_bounds__(256) void cast_kernel(const float* __restrict__ in,
                                                   short* __restrict__ out, int n4) {
  int i = blockIdx.x * blockDim.x + threadIdx.x;
  if (i < n4) {
    float4 v = ((const float4*)in)[i];
    short4v o;
    o.x = f2bf(v.x); o.y = f2bf(v.y); o.z = f2bf(v.z); o.w = f2bf(v.w);
    ((short4v*)out)[i] = o;
  }
}

// -------- DCT matrix: D[k][n] = 2*cos(pi/(2N) * k * (2n+1)), N=1024 -------
__global__ __launch_bounds__(256) void build_D(short* __restrict__ D) {
  int t = blockIdx.x * 256 + threadIdx.x;   // 1024*1024 total
  int k = t >> 10, n = t & 1023;
  const float s = 1.5339807878856412e-03f;  // pi/2048
  float arg = (s * (float)k) * (float)(2 * n + 1);
  D[t] = f2bf(2.0f * cosf(arg));
}

// -------- fold 8 row-block partials -> per-(b,c) mu, rstd -----------------
__global__ __launch_bounds__(256) void ln_stats(const float2* __restrict__ partial,
                                                float2* __restrict__ musd) {
  int n = blockIdx.x * 256 + threadIdx.x;   // 16384
  float S = 0.f, Q = 0.f;
#pragma unroll
  for (int r = 0; r < 8; ++r) {
    float2 p = partial[(size_t)r * 16384 + n];
    S += p.x; Q += p.y;
  }
  float mu  = S * (1.f / 1024.f);
  float var = Q * (1.f / 1024.f) - mu * mu;   // biased, like nn.LayerNorm
  float2 o; o.x = mu; o.y = rsqrtf(var + 1e-6f);
  musd[n] = o;
}

// -------- streaming LN apply: freqT[b][k][c] in place, short8/thread ------
__global__ __launch_bounds__(256) void ln_apply(short* __restrict__ freqT,
                                                const float2* __restrict__ musd,
                                                const float* __restrict__ lnw,
                                                const float* __restrict__ lnb) {
  int t = blockIdx.x * 256 + threadIdx.x;   // 2,097,152 threads
  int c8 = t & 63;            // c chunk (8 elems)
  int k  = (t >> 6) & 1023;
  int b  = t >> 16;
  size_t idx = ((size_t)b << 19) + (size_t)k * 512 + (size_t)c8 * 8;
  short8 v = *(const short8*)&freqT[idx];
  float w  = lnw[k];
  float bb = lnb[k];
  const float2* ms = &musd[b * 512 + c8 * 8];
  short8 o;
#pragma unroll
  for (int j = 0; j < 8; ++j) {
    float f = bf2f(v[j]);
    float2 m = ms[j];
    o[j] = f2bf((f - m.x) * m.y * w + bb);
  }
  *(short8*)&freqT[idx] = o;
}

// -------- BT-form bf16 GEMM: C[m,n] = sum_k A[m,k]*B[n,k] -----------------
// 128x128 tile, BK=32, 4 waves (2x2), 16x16x32 MFMA, global_load_lds staging.
// Flat grid + XCD-chunked bijective swizzle (T1/m204): wgid=(orig%8)*q+orig/8
// so consecutive wgids (which share operand panels) run on the SAME XCD.
// EPI 0: grid 1024: bx=wgid&7 (D tile), by=wgid>>3 (x panel shared by 8)
//        C -> freqT[b][r][c] bf16; also per-col sum/sumsq -> P
// EPI 1: grid 2048: by=wgid&7 (w1 tile), bx=(wgid>>3)&7, bz=wgid>>6
//        (8 consecutive wgids share the freqT A-panel)  relu -> z1t bf16
// EPI 2: grid 1024: bx=wgid&3 (w2 tile), by=(wgid>>2)&7, bz=wgid>>5
//        (4 consecutive wgids share the z1t B-panel)
//        out[bz][r][col] = X[same] * sigmoid(C), fp32
template<int EPI>
__global__ __launch_bounds__(256) void gemm_bt(
    const short* __restrict__ A, const short* __restrict__ B,
    void* __restrict__ Cout, const float* __restrict__ X,
    float2* __restrict__ P,
    int K, long strideA, long strideB)
{
  __shared__ short As[128 * 32];
  __shared__ short Bs[128 * 32];
  const int tid  = threadIdx.x;
  const int lane = tid & 63;
  const int wave = tid >> 6;
  const int wr = wave >> 1, wc = wave & 1;

  // ---- T1 bijective XCD swizzle (all grids divisible by 8) ----
  const int nwg  = gridDim.x;
  const int q    = nwg >> 3;
  const int orig = blockIdx.x;
  const int wgid = (orig & 7) * q + (orig >> 3);
  int bx, by, bz;
  if (EPI == 0)      { bx = wgid & 7;  by = wgid >> 3;        bz = 0; }
  else if (EPI == 1) { by = wgid & 7;  bx = (wgid >> 3) & 7;  bz = wgid >> 6; }
  else               { bx = wgid & 3;  by = (wgid >> 2) & 7;  bz = wgid >> 5; }

  const long row0 = (long)bx * 128;
  const long col0 = (long)by * 128;
  const short* Ab = A + (size_t)bz * strideA + (size_t)row0 * K;
  const short* Bb = B + (size_t)bz * strideB + (size_t)col0 * K;

  f32x4 acc[4][4];
#pragma unroll
  for (int i = 0; i < 4; ++i)
#pragma unroll
    for (int j = 0; j < 4; ++j) acc[i][j] = (f32x4){0.f, 0.f, 0.f, 0.f};

  const int lr = lane & 15;
  const int lk = (lane >> 4) * 8;

  for (int k0 = 0; k0 < K; k0 += 32) {
#pragma unroll
    for (int i = 0; i < 2; ++i) {
      int ci = i * 256 + tid;              // chunk id 0..511 (16B chunks)
      int rr = ci >> 2;                    // tile row
      int kc = (ci & 3) * 8;               // k offset within BK
      __builtin_amdgcn_global_load_lds(
          (const __attribute__((address_space(1))) void*)(Ab + (size_t)rr * K + k0 + kc),
          (__attribute__((address_space(3))) void*)(As + ci * 8), 16, 0, 0);
      __builtin_amdgcn_global_load_lds(
          (const __attribute__((address_space(1))) void*)(Bb + (size_t)rr * K + k0 + kc),
          (__attribute__((address_space(3))) void*)(Bs + ci * 8), 16, 0, 0);
    }
    __syncthreads();

    short8 af[4], bfv[4];
#pragma unroll
    for (int mi = 0; mi < 4; ++mi)
      af[mi] = *(const short8*)&As[(wr * 64 + mi * 16 + lr) * 32 + lk];
#pragma unroll
    for (int ni = 0; ni < 4; ++ni)
      bfv[ni] = *(const short8*)&Bs[(wc * 64 + ni * 16 + lr) * 32 + lk];
#pragma unroll
    for (int mi = 0; mi < 4; ++mi)
#pragma unroll
      for (int ni = 0; ni < 4; ++ni)
        acc[mi][ni] = __builtin_amdgcn_mfma_f32_16x16x32_bf16(af[mi], bfv[ni], acc[mi][ni], 0, 0, 0);
    __syncthreads();
  }

  const int rbase = (int)row0 + wr * 64 + ((lane >> 4) << 2);
  const int cbase = (int)col0 + wc * 64 + lr;

  float s[4], qq[4];
#pragma unroll
  for (int ni = 0; ni < 4; ++ni) { s[ni] = 0.f; qq[ni] = 0.f; }

#pragma unroll
  for (int mi = 0; mi < 4; ++mi) {
#pragma unroll
    for (int ni = 0; ni < 4; ++ni) {
#pragma unroll
      for (int j = 0; j < 4; ++j) {
        int r  = rbase + mi * 16 + j;
        int cc = cbase + ni * 16;
        float v = acc[mi][ni][j];
        if (EPI == 0) {
          s[ni] += v; qq[ni] += v * v;
          size_t idx = ((size_t)(cc >> 9) << 19) + (size_t)r * 512 + (size_t)(cc & 511);
          ((short*)Cout)[idx] = f2bf(v);
        } else if (EPI == 1) {
          size_t idx = (size_t)bz * 1048576 + (size_t)r * 1024 + (size_t)cc;
          ((short*)Cout)[idx] = f2bf(v > 0.f ? v : 0.f);
        } else {
          size_t idx = (size_t)bz * 524288 + (size_t)r * 1024 + (size_t)cc;
          float g = 1.f / (1.f + __expf(-v));
          ((float*)Cout)[idx] = X[idx] * g;
        }
      }
    }
  }

  if (EPI == 0) {
    // Reduce per-column sum/sumsq over the block's 128 rows.
    float* redS = (float*)As;   // [128 cols][8 contributors]
    float* redQ = (float*)Bs;
    const int contrib = wr * 4 + (lane >> 4);
#pragma unroll
    for (int ni = 0; ni < 4; ++ni) {
      int ccl = wc * 64 + ni * 16 + lr;    // 0..127 within block
      redS[ccl * 8 + contrib] = s[ni];
      redQ[ccl * 8 + contrib] = qq[ni];
    }
    __syncthreads();
    if (tid < 128) {
      float S = 0.f, Q = 0.f;
#pragma unroll
      for (int i = 0; i < 8; ++i) { S += redS[tid * 8 + i]; Q += redQ[tid * 8 + i]; }
      float2 o; o.x = S; o.y = Q;
      P[(size_t)bx * 16384 + col0 + tid] = o;
    }
  }
}

extern "C" void kernel_launch(void* const* d_in, const int* in_sizes, int n_in,
                              void* d_out, int out_size, void* d_ws, size_t ws_size,
                              hipStream_t stream) {
  const float* x    = (const float*)d_in[0];   // [32,512,1024]
  const float* w1   = (const float*)d_in[1];   // [1024,512]
  const float* w2   = (const float*)d_in[2];   // [512,1024]
  const float* ln_w = (const float*)d_in[3];   // [1024]
  const float* ln_b = (const float*)d_in[4];   // [1024]
  float* out = (float*)d_out;

  char* ws = (char*)d_ws;
  short* x_bf   = (short*)(ws);                  // 33,554,432 B
  short* D_bf   = (short*)(ws + 33554432);       //  2,097,152 B
  short* w1_bf  = (short*)(ws + 35651584);       //  1,048,576 B
  short* w2_bf  = (short*)(ws + 36700160);       //  1,048,576 B
  short* freqT  = (short*)(ws + 37748736);       // 33,554,432 B  [b][k][c]
  short* z1t    = (short*)(ws + 71303168);       // 67,108,864 B  [b][p][o]
  float2* part  = (float2*)(ws + 138412032);     //  1,048,576 B  [8][16384]
  float2* musd  = (float2*)(ws + 139460608);     //    131,072 B  [16384]
  // total ~139.6 MB

  cast_kernel<<<dim3(16384), dim3(256), 0, stream>>>(x,  x_bf,  16777216 / 4);
  cast_kernel<<<dim3(512),   dim3(256), 0, stream>>>(w1, w1_bf, 524288 / 4);
  cast_kernel<<<dim3(512),   dim3(256), 0, stream>>>(w2, w2_bf, 524288 / 4);
  build_D<<<dim3(4096), dim3(256), 0, stream>>>(D_bf);

  // GEMM1: C[k,(b,c)] = sum_n D[k,n] * x[(b,c),n] -> freqT[b][k][c] + LN partials
  gemm_bt<0><<<dim3(1024), dim3(256), 0, stream>>>(
      D_bf, x_bf, (void*)freqT, nullptr, part, 1024, 0, 0);

  // LN stats: fold 8 row-block partials -> (mu, rstd) per (b,c)
  ln_stats<<<dim3(64), dim3(256), 0, stream>>>(part, musd);

  // LN apply: normalize freqT in place (streaming, vectorized)
  ln_apply<<<dim3(8192), dim3(256), 0, stream>>>(freqT, musd, ln_w, ln_b);

  // GEMM2: C[p,o] = sum_c Ht[b][p,c] * w1[o,c], relu -> z1t[b][p][o]
  gemm_bt<1><<<dim3(2048), dim3(256), 0, stream>>>(
      freqT, w1_bf, (void*)z1t, nullptr, nullptr, 512, 524288, 0);

  // GEMM3: C[o2,p] = sum_j w2[o2,j] * z1t[b][p,j]; out = x * sigmoid(C)
  gemm_bt<2><<<dim3(1024), dim3(256), 0, stream>>>(
      w2_bf, z1t, (void*)out, x, nullptr, 1024, 0, 1048576);
}

// Round 4
// 192.988 us; speedup vs baseline: 1.6051x; 1.1211x over previous
//
#include <hip/hip_runtime.h>
#include <hip/hip_bf16.h>
#include <math.h>

typedef short short8 __attribute__((ext_vector_type(8)));
typedef short short4v __attribute__((ext_vector_type(4)));
typedef float f32x4 __attribute__((ext_vector_type(4)));

__device__ __forceinline__ short f2bf(float f) {
  union { float f; unsigned u; } v; v.f = f;
  unsigned r = v.u + 0x7FFFu + ((v.u >> 16) & 1u);
  return (short)(r >> 16);
}
__device__ __forceinline__ float bf2f(short s) {
  union { unsigned u; float f; } v; v.u = ((unsigned)(unsigned short)s) << 16;
  return v.f;
}

// -------- generic f32 -> bf16 cast, 4 elems/thread -----------------------
__global__ __launch_bounds__(256) void cast_kernel(const float* __restrict__ in,
                                                   short* __restrict__ out, int n4) {
  int i = blockIdx.x * blockDim.x + threadIdx.x;
  if (i < n4) {
    float4 v = ((const float4*)in)[i];
    short4v o;
    o.x = f2bf(v.x); o.y = f2bf(v.y); o.z = f2bf(v.z); o.w = f2bf(v.w);
    ((short4v*)out)[i] = o;
  }
}

// -------- DCT matrix: D[k][n] = 2*cos(pi/(2N) * k * (2n+1)), N=1024 -------
__global__ __launch_bounds__(256) void build_D(short* __restrict__ D) {
  int t = blockIdx.x * 256 + threadIdx.x;
  int k = t >> 10, n = t & 1023;
  const float s = 1.5339807878856412e-03f;  // pi/2048
  float arg = (s * (float)k) * (float)(2 * n + 1);
  D[t] = f2bf(2.0f * cosf(arg));
}

// -------- fold 4 row-block partials -> per-(b,c) mu, rstd -----------------
__global__ __launch_bounds__(256) void ln_stats(const float2* __restrict__ partial,
                                                float2* __restrict__ musd) {
  int n = blockIdx.x * 256 + threadIdx.x;   // 16384
  float S = 0.f, Q = 0.f;
#pragma unroll
  for (int r = 0; r < 4; ++r) {
    float2 p = partial[(size_t)r * 16384 + n];
    S += p.x; Q += p.y;
  }
  float mu  = S * (1.f / 1024.f);
  float var = Q * (1.f / 1024.f) - mu * mu;   // biased, like nn.LayerNorm
  float2 o; o.x = mu; o.y = rsqrtf(var + 1e-6f);
  musd[n] = o;
}

// -------- streaming LN apply: freqT[b][k][c] in place, short8/thread ------
__global__ __launch_bounds__(256) void ln_apply(short* __restrict__ freqT,
                                                const float2* __restrict__ musd,
                                                const float* __restrict__ lnw,
                                                const float* __restrict__ lnb) {
  int t = blockIdx.x * 256 + threadIdx.x;
  int c8 = t & 63;
  int k  = (t >> 6) & 1023;
  int b  = t >> 16;
  size_t idx = ((size_t)b << 19) + (size_t)k * 512 + (size_t)c8 * 8;
  short8 v = *(const short8*)&freqT[idx];
  float w  = lnw[k];
  float bb = lnb[k];
  const float2* ms = &musd[b * 512 + c8 * 8];
  short8 o;
#pragma unroll
  for (int j = 0; j < 8; ++j) {
    float f = bf2f(v[j]);
    float2 m = ms[j];
    o[j] = f2bf((f - m.x) * m.y * w + bb);
  }
  *(short8*)&freqT[idx] = o;
}

// ======== 256x256 pipelined BT-GEMM: C[m,n] = sum_k A[m,k]*B[n,k] =========
// BK=64, 8 waves (2Mx4N), per-wave 128x64 output, acc[8][4] f32x4.
// Double-buffered 128KiB LDS; counted vmcnt(8) (never 0 mid-loop); raw
// s_barrier; 4 phases/K-tile {ds_read; barrier; lgkmcnt(0); setprio(1);
// 16 MFMA; setprio(0); barrier}; stage(kt+2) after last phase barrier.
// T2 swizzle: physical 16B slot = logical ^ (row&7); write side realized by
// inverse-permuting the GLOBAL source (global_load_lds dest stays linear
// = base + lane*16); read side XORs the slot.
template<int EPI>
__global__ __launch_bounds__(512, 2) void gemm256(
    const short* __restrict__ A, const short* __restrict__ B,
    void* __restrict__ Cout, const float* __restrict__ X,
    float2* __restrict__ P, int K, int NT, long strideA, long strideB)
{
  __shared__ short As[2][16384];
  __shared__ short Bs[2][16384];
  const int tid = threadIdx.x;
  const int l   = tid & 63;
  const int w   = tid >> 6;        // wave 0..7
  const int wm  = w >> 2;          // 0..1
  const int wn  = w & 3;           // 0..3
  const int l7  = l & 7;
  const int lr  = l & 15;
  const int lhi = l >> 4;

  // ---- T1 bijective XCD swizzle ----
  const int nwg = gridDim.x, q = nwg >> 3, orig = blockIdx.x;
  const int wgid = (orig & 7) * q + (orig >> 3);
  int bx, by, bz;
  if (EPI == 0)      { bx = wgid & 3; by = wgid >> 2;      bz = 0; }
  else if (EPI == 1) { bx = wgid & 3; by = (wgid >> 2) & 3; bz = wgid >> 4; }
  else               { by = wgid & 3; bx = (wgid >> 2) & 1; bz = wgid >> 3; }

  const long row0 = (long)bx * 256, col0 = (long)by * 256;
  const short* Ab = A + (size_t)bz * strideA + (size_t)row0 * K;
  const short* Bb = B + (size_t)bz * strideB + (size_t)col0 * K;

  // staging geometry: round r covers rows [r*64, r*64+64); thread -> row
  // rowb = w*8 + (l>>3), 16B slot (l&7). Inverse-swizzled source column.
  const int rowb  = w * 8 + (l >> 3);
  const int colel = (l7 ^ (l >> 3)) * 8;            // (slot ^ row&7)*8 elems
  // fragment read offsets (elements); phys slot = (ks*4+lhi) ^ (row&7=l&7)
  const int arow = (wm * 128 + lr) * 64;
  const int brow = (wn * 64  + lr) * 64;
  const int sk0 = ((lhi    ) ^ l7) * 8;
  const int sk1 = ((lhi + 4) ^ l7) * 8;

  f32x4 acc[8][4];
#pragma unroll
  for (int i = 0; i < 8; ++i)
#pragma unroll
    for (int j = 0; j < 4; ++j) acc[i][j] = (f32x4){0.f, 0.f, 0.f, 0.f};

#define STAGE(KT, D) do {                                                    \
    const size_t ko_ = (size_t)(KT) * 64 + colel;                            \
    _Pragma("unroll")                                                        \
    for (int r_ = 0; r_ < 4; ++r_)                                           \
      __builtin_amdgcn_global_load_lds(                                      \
        (const __attribute__((address_space(1))) void*)(Ab + (size_t)(r_*64 + rowb)*K + ko_), \
        (__attribute__((address_space(3))) void*)(&As[D][r_*4096 + w*512 + l*8]), 16, 0, 0);  \
    _Pragma("unroll")                                                        \
    for (int r_ = 0; r_ < 4; ++r_)                                           \
      __builtin_amdgcn_global_load_lds(                                      \
        (const __attribute__((address_space(1))) void*)(Bb + (size_t)(r_*64 + rowb)*K + ko_), \
        (__attribute__((address_space(3))) void*)(&Bs[D][r_*4096 + w*512 + l*8]), 16, 0, 0);  \
  } while (0)

  STAGE(0, 0);
  STAGE(1, 1);

  short8 b0, b1, b2, b3;
  int cur = 0;
  for (int kt = 0; kt < NT; ++kt) {
    if (kt + 1 < NT) { asm volatile("s_waitcnt vmcnt(8)" ::: "memory"); }
    else             { asm volatile("s_waitcnt vmcnt(0)" ::: "memory"); }
    __builtin_amdgcn_sched_barrier(0);
    __builtin_amdgcn_s_barrier();          // all waves' kt-loads landed
    const short* Ad = As[cur];
    const short* Bd = Bs[cur];
    short8 a0, a1, a2, a3;

#define MFMA_ROW(MI, AV)                                                       \
    acc[MI][0] = __builtin_amdgcn_mfma_f32_16x16x32_bf16(AV, b0, acc[MI][0], 0, 0, 0); \
    acc[MI][1] = __builtin_amdgcn_mfma_f32_16x16x32_bf16(AV, b1, acc[MI][1], 0, 0, 0); \
    acc[MI][2] = __builtin_amdgcn_mfma_f32_16x16x32_bf16(AV, b2, acc[MI][2], 0, 0, 0); \
    acc[MI][3] = __builtin_amdgcn_mfma_f32_16x16x32_bf16(AV, b3, acc[MI][3], 0, 0, 0);

#define PH(MIBASE, SK, LOADB)                                                \
    a0 = *(const short8*)&Ad[arow + (MIBASE + 0) * 1024 + SK];               \
    a1 = *(const short8*)&Ad[arow + (MIBASE + 1) * 1024 + SK];               \
    a2 = *(const short8*)&Ad[arow + (MIBASE + 2) * 1024 + SK];               \
    a3 = *(const short8*)&Ad[arow + (MIBASE + 3) * 1024 + SK];               \
    if (LOADB) {                                                             \
      b0 = *(const short8*)&Bd[brow + 0 * 1024 + SK];                        \
      b1 = *(const short8*)&Bd[brow + 1 * 1024 + SK];                        \
      b2 = *(const short8*)&Bd[brow + 2 * 1024 + SK];                        \
      b3 = *(const short8*)&Bd[brow + 3 * 1024 + SK];                        \
    }                                                                        \
    __builtin_amdgcn_s_barrier();                                            \
    asm volatile("s_waitcnt lgkmcnt(0)" ::: "memory");                       \
    __builtin_amdgcn_sched_barrier(0);                                       \
    __builtin_amdgcn_s_setprio(1);                                           \
    MFMA_ROW(MIBASE + 0, a0); MFMA_ROW(MIBASE + 1, a1);                      \
    MFMA_ROW(MIBASE + 2, a2); MFMA_ROW(MIBASE + 3, a3);                      \
    __builtin_amdgcn_s_setprio(0);                                           \
    __builtin_amdgcn_sched_barrier(0);                                       \
    __builtin_amdgcn_s_barrier();

    PH(0, sk0, 1)
    PH(4, sk0, 0)
    PH(0, sk1, 1)
    PH(4, sk1, 0)

    if (kt + 2 < NT) STAGE(kt + 2, cur);
    cur ^= 1;
  }

  // ---------------- epilogue ----------------
  const int rb = (int)row0 + wm * 128 + lhi * 4;
  const int cb = (int)col0 + wn * 64 + lr;
  float sv[4], qv[4];
#pragma unroll
  for (int ni = 0; ni < 4; ++ni) { sv[ni] = 0.f; qv[ni] = 0.f; }

#pragma unroll
  for (int mi = 0; mi < 8; ++mi) {
#pragma unroll
    for (int ni = 0; ni < 4; ++ni) {
#pragma unroll
      for (int j = 0; j < 4; ++j) {
        int r  = rb + mi * 16 + j;
        int cc = cb + ni * 16;
        float v = acc[mi][ni][j];
        if (EPI == 0) {
          sv[ni] += v; qv[ni] += v * v;
          ((short*)Cout)[((size_t)(cc >> 9) << 19) + (size_t)r * 512 + (cc & 511)] = f2bf(v);
        } else if (EPI == 1) {
          ((short*)Cout)[(size_t)bz * 1048576 + (size_t)r * 1024 + cc] = f2bf(v > 0.f ? v : 0.f);
        } else {
          size_t idx = (size_t)bz * 524288 + (size_t)r * 1024 + cc;
          float g = 1.f / (1.f + __expf(-v));
          ((float*)Cout)[idx] = X[idx] * g;
        }
      }
    }
  }

  if (EPI == 0) {
    __syncthreads();
    float* redS = (float*)&As[0][0];       // [256 cols][8 contributors]
    float* redQ = redS + 2048;
    const int contrib = wm * 4 + lhi;
#pragma unroll
    for (int ni = 0; ni < 4; ++ni) {
      int ccl = wn * 64 + ni * 16 + lr;
      redS[ccl * 8 + contrib] = sv[ni];
      redQ[ccl * 8 + contrib] = qv[ni];
    }
    __syncthreads();
    if (tid < 256) {
      float S = 0.f, Q = 0.f;
#pragma unroll
      for (int i = 0; i < 8; ++i) { S += redS[tid * 8 + i]; Q += redQ[tid * 8 + i]; }
      float2 o; o.x = S; o.y = Q;
      P[(size_t)bx * 16384 + col0 + tid] = o;
    }
  }
#undef PH
#undef MFMA_ROW
#undef STAGE
}

extern "C" void kernel_launch(void* const* d_in, const int* in_sizes, int n_in,
                              void* d_out, int out_size, void* d_ws, size_t ws_size,
                              hipStream_t stream) {
  const float* x    = (const float*)d_in[0];   // [32,512,1024]
  const float* w1   = (const float*)d_in[1];   // [1024,512]
  const float* w2   = (const float*)d_in[2];   // [512,1024]
  const float* ln_w = (const float*)d_in[3];   // [1024]
  const float* ln_b = (const float*)d_in[4];   // [1024]
  float* out = (float*)d_out;

  char* ws = (char*)d_ws;
  short* x_bf   = (short*)(ws);                  // 33,554,432 B
  short* D_bf   = (short*)(ws + 33554432);       //  2,097,152 B
  short* w1_bf  = (short*)(ws + 35651584);       //  1,048,576 B
  short* w2_bf  = (short*)(ws + 36700160);       //  1,048,576 B
  short* freqT  = (short*)(ws + 37748736);       // 33,554,432 B  [b][k][c]
  short* z1t    = (short*)(ws + 71303168);       // 67,108,864 B  [b][p][o]
  float2* part  = (float2*)(ws + 138412032);     //    524,288 B  [4][16384]
  float2* musd  = (float2*)(ws + 139460608);     //    131,072 B  [16384]

  cast_kernel<<<dim3(16384), dim3(256), 0, stream>>>(x,  x_bf,  16777216 / 4);
  cast_kernel<<<dim3(512),   dim3(256), 0, stream>>>(w1, w1_bf, 524288 / 4);
  cast_kernel<<<dim3(512),   dim3(256), 0, stream>>>(w2, w2_bf, 524288 / 4);
  build_D<<<dim3(4096), dim3(256), 0, stream>>>(D_bf);

  // GEMM1: C[k,(b,c)] = sum_n D[k,n] * x[(b,c),n] -> freqT + LN partials
  gemm256<0><<<dim3(256), dim3(512), 0, stream>>>(
      D_bf, x_bf, (void*)freqT, nullptr, part, 1024, 16, 0, 0);

  // LN stats: fold 4 row-block partials -> (mu, rstd) per (b,c)
  ln_stats<<<dim3(64), dim3(256), 0, stream>>>(part, musd);

  // LN apply: normalize freqT in place (streaming, vectorized)
  ln_apply<<<dim3(8192), dim3(256), 0, stream>>>(freqT, musd, ln_w, ln_b);

  // GEMM2: C[p,o] = sum_c Ht[b][p,c] * w1[o,c], relu -> z1t[b][p][o]
  gemm256<1><<<dim3(512), dim3(512), 0, stream>>>(
      freqT, w1_bf, (void*)z1t, nullptr, nullptr, 512, 8, 524288, 0);

  // GEMM3: C[o2,p] = sum_j w2[o2,j] * z1t[b][p,j]; out = x * sigmoid(C)
  gemm256<2><<<dim3(256), dim3(512), 0, stream>>>(
      w2_bf, z1t, (void*)out, x, nullptr, 1024, 16, 0, 1048576);
}